// Round 2
// baseline (88.316 us; speedup 1.0000x reference)
//
#include <hip/hip_runtime.h>
#include <hip/hip_bf16.h>

#define N_NODES 10000
#define IN_CH 128
#define HID 256
#define E_TAR 8192
#define N_EDGES 320000
#define WPR 320          // bitmask words per row (313 used, padded)
#define WUSED 313
#define MAXCN 256
#define MASK_WORDS (N_NODES * WPR)   // 3,200,000 words = 12.8 MB

typedef short bf16x8 __attribute__((ext_vector_type(8)));
typedef float f32x4 __attribute__((ext_vector_type(4)));

__device__ __forceinline__ unsigned short f2bf(float f) {
  union { float f; unsigned u; } v; v.f = f;
  unsigned r = v.u + 0x7fffu + ((v.u >> 16) & 1u);  // RNE
  return (unsigned short)(r >> 16);
}

// fast zero of the adjacency bitmask: 16B per lane, grid-stride.
__global__ void fill_zero(uint4* __restrict__ p, int n4) {
  int i = blockIdx.x * 256 + threadIdx.x;
  int stride = gridDim.x * 256;
  uint4 z = {0u, 0u, 0u, 0u};
  for (; i < n4; i += stride) p[i] = z;
}

__global__ void scatter_adj(const int* __restrict__ row, const int* __restrict__ col,
                            unsigned* __restrict__ mask) {
  int k = blockIdx.x * 256 + threadIdx.x;
  if (k < N_EDGES) {
    int r = row[k], c = col[k];
    atomicOr(&mask[(size_t)r * WPR + (c >> 5)], 1u << (c & 31));
  }
}

// one block (128 threads) per target edge: AND the two adjacency rows,
// list common neighbors in LDS, then channel-parallel feature sum.
__global__ void cn_gather(const unsigned* __restrict__ mask, const int* __restrict__ tar,
                          const float* __restrict__ x, float* __restrict__ cnx) {
  __shared__ int cnt;
  __shared__ int list[MAXCN];
  int e = blockIdx.x;
  int i = tar[e], j = tar[E_TAR + e];
  if (threadIdx.x == 0) cnt = 0;
  __syncthreads();
  const unsigned* mi = mask + (size_t)i * WPR;
  const unsigned* mj = mask + (size_t)j * WPR;
  for (int w = threadIdx.x; w < WUSED; w += 128) {
    unsigned v = mi[w] & mj[w];
    while (v) {
      int b = __ffs(v) - 1;
      v &= v - 1;
      int pos = atomicAdd(&cnt, 1);
      if (pos < MAXCN) list[pos] = w * 32 + b;
    }
  }
  __syncthreads();
  int n = cnt; if (n > MAXCN) n = MAXCN;
  int c = threadIdx.x;             // 128 threads == IN_CH channels
  float acc = 0.f;
  for (int t = 0; t < n; ++t) acc += x[(size_t)list[t] * IN_CH + c];
  cnx[(size_t)e * IN_CH + c] = acc;
}

// C[M,N] = f(A @ W + bias [+ scale*extra]); A is [M,K] f32, or fused xi*xj
// gather when tar != nullptr. W is [K,N] f32 row-major. bf16 MFMA 16x16x32.
// 64x64 tile, 256 threads = 4 waves in 2x2, BK=32.
__global__ __launch_bounds__(256) void gemm_mfma(
    const float* __restrict__ A, const float* __restrict__ W,
    const float* __restrict__ bias, const float* __restrict__ extra,
    const float* __restrict__ scalePtr, const int* __restrict__ tar,
    const float* __restrict__ x, int relu, int M, int N, int K,
    float* __restrict__ C)
{
  __shared__ unsigned short As[64][56];   // 112B row stride: 16B-aligned, ~2-way banks
  __shared__ unsigned short Bs[64][56];   // Bs[n][k] (W staged transposed)
  int m0 = blockIdx.x * 64;
  int n0 = blockIdx.y * 64;
  int tid = threadIdx.x;
  int lane = tid & 63, wv = tid >> 6;
  int wm0 = (wv >> 1) * 32, wn0 = (wv & 1) * 32;
  f32x4 acc[2][2] = {};

  int arow = tid >> 2, akb = (tid & 3) * 8;   // A staging: row arow, k akb..akb+7
  int bn = tid & 63, bkb = (tid >> 6) * 8;    // B staging: col bn, k bkb..bkb+7
  int gi = 0, gj = 0;
  if (tar) { gi = tar[m0 + arow]; gj = tar[E_TAR + m0 + arow]; }

  for (int k0 = 0; k0 < K; k0 += 32) {
    float av[8];
    if (tar) {
      const float* xi = x + (size_t)gi * IN_CH + k0 + akb;
      const float* xj = x + (size_t)gj * IN_CH + k0 + akb;
      #pragma unroll
      for (int u = 0; u < 8; ++u) av[u] = xi[u] * xj[u];
    } else {
      const float* ap = A + (size_t)(m0 + arow) * K + k0 + akb;
      #pragma unroll
      for (int u = 0; u < 8; ++u) av[u] = ap[u];
    }
    unsigned short abf[8];
    #pragma unroll
    for (int u = 0; u < 8; ++u) abf[u] = f2bf(av[u]);
    *(bf16x8*)&As[arow][akb] = *(bf16x8*)abf;

    unsigned short bbf[8];
    #pragma unroll
    for (int u = 0; u < 8; ++u) bbf[u] = f2bf(W[(size_t)(k0 + bkb + u) * N + n0 + bn]);
    *(bf16x8*)&Bs[bn][bkb] = *(bf16x8*)bbf;
    __syncthreads();

    int l15 = lane & 15, kq = (lane >> 4) * 8;
    bf16x8 a0 = *(bf16x8*)&As[wm0 + l15][kq];
    bf16x8 a1 = *(bf16x8*)&As[wm0 + 16 + l15][kq];
    bf16x8 b0 = *(bf16x8*)&Bs[wn0 + l15][kq];
    bf16x8 b1 = *(bf16x8*)&Bs[wn0 + 16 + l15][kq];
    acc[0][0] = __builtin_amdgcn_mfma_f32_16x16x32_bf16(a0, b0, acc[0][0], 0, 0, 0);
    acc[0][1] = __builtin_amdgcn_mfma_f32_16x16x32_bf16(a0, b1, acc[0][1], 0, 0, 0);
    acc[1][0] = __builtin_amdgcn_mfma_f32_16x16x32_bf16(a1, b0, acc[1][0], 0, 0, 0);
    acc[1][1] = __builtin_amdgcn_mfma_f32_16x16x32_bf16(a1, b1, acc[1][1], 0, 0, 0);
    __syncthreads();
  }

  float scale = scalePtr ? scalePtr[0] : 0.f;
  int l15 = lane & 15, rq = (lane >> 4) * 4;
  #pragma unroll
  for (int fm = 0; fm < 2; ++fm) {
    #pragma unroll
    for (int fn = 0; fn < 2; ++fn) {
      int cg = n0 + wn0 + fn * 16 + l15;
      float bv = bias[cg];
      #pragma unroll
      for (int i2 = 0; i2 < 4; ++i2) {
        int rg = m0 + wm0 + fm * 16 + rq + i2;
        float v = acc[fm][fn][i2] + bv;
        if (extra) v += scale * extra[(size_t)rg * N + cg];
        if (relu) v = fmaxf(v, 0.f);
        C[(size_t)rg * N + cg] = v;
      }
    }
  }
}

// out[row] = h[row,:] . Wl2 + bl2 ; one wave per row
__global__ void final_dot(const float* __restrict__ h, const float* __restrict__ w2,
                          const float* __restrict__ b2, float* __restrict__ out) {
  int wv = threadIdx.x >> 6, lane = threadIdx.x & 63;
  int row = blockIdx.x * 4 + wv;
  const float* hr = h + (size_t)row * HID;
  float s = 0.f;
  #pragma unroll
  for (int t = 0; t < 4; ++t) s += hr[lane + 64 * t] * w2[lane + 64 * t];
  #pragma unroll
  for (int off = 32; off; off >>= 1) s += __shfl_down(s, off);
  if (lane == 0) out[row] = s + b2[0];
}

extern "C" void kernel_launch(void* const* d_in, const int* in_sizes, int n_in,
                              void* d_out, int out_size, void* d_ws, size_t ws_size,
                              hipStream_t stream) {
  const float* x      = (const float*)d_in[0];
  const int*   adj_r  = (const int*)d_in[1];
  const int*   adj_c  = (const int*)d_in[2];
  const int*   tar    = (const int*)d_in[3];
  const float* beta   = (const float*)d_in[4];
  const float* W1     = (const float*)d_in[5];
  const float* b1     = (const float*)d_in[6];
  const float* W2     = (const float*)d_in[7];
  const float* b2     = (const float*)d_in[8];
  const float* W3     = (const float*)d_in[9];
  const float* b3     = (const float*)d_in[10];
  const float* Wij1   = (const float*)d_in[11];
  const float* bij1   = (const float*)d_in[12];
  const float* Wij2   = (const float*)d_in[13];
  const float* bij2   = (const float*)d_in[14];
  const float* Wl1    = (const float*)d_in[15];
  const float* bl1    = (const float*)d_in[16];
  const float* Wl2    = (const float*)d_in[17];
  const float* bl2    = (const float*)d_in[18];

  char* ws = (char*)d_ws;
  unsigned* mask = (unsigned*)ws;                          // 12.8 MB
  float* bufA = (float*)(ws + (size_t)16 * 1024 * 1024);   // 8 MB each
  float* bufB = (float*)(ws + (size_t)24 * 1024 * 1024);
  float* bufC = (float*)(ws + (size_t)32 * 1024 * 1024);

  // zero the bitmask ourselves: rocclr fillBuffer ran at 325 GB/s (39.5 us).
  fill_zero<<<3200, 256, 0, stream>>>((uint4*)mask, MASK_WORDS / 4);
  scatter_adj<<<(N_EDGES + 255) / 256, 256, 0, stream>>>(adj_r, adj_c, mask);
  cn_gather<<<E_TAR, 128, 0, stream>>>(mask, tar, x, bufA);

  dim3 g(E_TAR / 64, HID / 64);  // 128 x 4
  // t1 = relu(cn_x @ W1 + b1)
  gemm_mfma<<<g, 256, 0, stream>>>(bufA, W1, b1, nullptr, nullptr, nullptr, nullptr, 1, E_TAR, HID, IN_CH, bufB);
  // t2 = relu(t1 @ W2 + b2)
  gemm_mfma<<<g, 256, 0, stream>>>(bufB, W2, b2, nullptr, nullptr, nullptr, nullptr, 1, E_TAR, HID, HID, bufC);
  // xcn = t2 @ W3 + b3
  gemm_mfma<<<g, 256, 0, stream>>>(bufC, W3, b3, nullptr, nullptr, nullptr, nullptr, 0, E_TAR, HID, HID, bufB);
  // u1 = relu((xi*xj) @ Wij1 + bij1)   (fused gather-product A)
  gemm_mfma<<<g, 256, 0, stream>>>(nullptr, Wij1, bij1, nullptr, nullptr, tar, x, 1, E_TAR, HID, IN_CH, bufC);
  // v = (u1 @ Wij2 + bij2) + beta * xcn
  gemm_mfma<<<g, 256, 0, stream>>>(bufC, Wij2, bij2, bufB, beta, nullptr, nullptr, 0, E_TAR, HID, HID, bufA);
  // h = relu(v @ Wl1 + bl1)
  gemm_mfma<<<g, 256, 0, stream>>>(bufA, Wl1, bl1, nullptr, nullptr, nullptr, nullptr, 1, E_TAR, HID, HID, bufC);
  // out = h @ Wl2 + bl2
  final_dot<<<E_TAR / 4, 256, 0, stream>>>(bufC, Wl2, bl2, (float*)d_out);
}

// Round 3
// 82.763 us; speedup vs baseline: 1.0671x; 1.0671x over previous
//
#include <hip/hip_runtime.h>
#include <hip/hip_bf16.h>

#define N_NODES 10000
#define IN_CH 128
#define HID 256
#define E_TAR 8192
#define N_EDGES 320000
#define WPR 320          // bitmask words per row (313 used, padded)
#define WUSED 313
#define MASK_WORDS (N_NODES * WPR)   // 12.8 MB
#define CSR_MAX 128
#define BM 32

typedef short bf16x8 __attribute__((ext_vector_type(8)));
typedef short bf16x4 __attribute__((ext_vector_type(4)));
typedef float f32x4 __attribute__((ext_vector_type(4)));

__device__ __forceinline__ unsigned short f2bf(float f) {
  union { float f; unsigned u; } v; v.f = f;
  unsigned r = v.u + 0x7fffu + ((v.u >> 16) & 1u);  // RNE
  return (unsigned short)(r >> 16);
}
__device__ __forceinline__ float bf2f(unsigned short h) {
  union { unsigned u; float f; } v; v.u = ((unsigned)h) << 16; return v.f;
}

// ---------- adjacency bitmask ----------
__global__ void fill_zero(uint4* __restrict__ p, int n4) {
  int i = blockIdx.x * 256 + threadIdx.x;
  int stride = gridDim.x * 256;
  uint4 z = {0u, 0u, 0u, 0u};
  for (; i < n4; i += stride) p[i] = z;
}

__global__ void scatter_adj(const int* __restrict__ row, const int* __restrict__ col,
                            unsigned* __restrict__ mask) {
  int k = blockIdx.x * 256 + threadIdx.x;
  if (k < N_EDGES) {
    int r = row[k], c = col[k];
    atomicOr(&mask[(size_t)r * WPR + (c >> 5)], 1u << (c & 31));
  }
}

// ---------- CSR from bitmask (dedup'd): one wave per row ----------
__global__ void csr_build(const unsigned* __restrict__ mask, int* __restrict__ deg,
                          int* __restrict__ csr) {
  int row = blockIdx.x * 4 + (threadIdx.x >> 6);
  int lane = threadIdx.x & 63;
  const unsigned* mr = mask + (size_t)row * WPR;
  unsigned words[5];
  int cnt = 0;
  #pragma unroll
  for (int t = 0; t < 5; ++t) {
    int w = lane + 64 * t;
    unsigned v = (w < WUSED) ? mr[w] : 0u;
    words[t] = v;
    cnt += __popc(v);
  }
  // exclusive prefix over 64 lanes
  int pre = cnt;
  #pragma unroll
  for (int off = 1; off < 64; off <<= 1) {
    int n2 = __shfl_up(pre, off);
    if (lane >= off) pre += n2;
  }
  int excl = pre - cnt;
  int total = __shfl(pre, 63);
  if (lane == 0) deg[row] = total;
  int p = excl;
  int* dst = csr + (size_t)row * CSR_MAX;
  #pragma unroll
  for (int t = 0; t < 5; ++t) {
    unsigned v = words[t];
    int wbase = (lane + 64 * t) * 32;
    while (v) {
      int b = __ffs(v) - 1;
      v &= v - 1;
      if (p < CSR_MAX) dst[p] = wbase + b;
      ++p;
    }
  }
}

// ---------- common-neighbor gather: one wave per target edge ----------
__global__ void cn_gather_csr(const unsigned* __restrict__ mask, const int* __restrict__ deg,
                              const int* __restrict__ csr, const int* __restrict__ tar,
                              const float* __restrict__ x, float* __restrict__ cnx) {
  __shared__ int lists[4][256];
  __shared__ int cnts[4];
  int wv = threadIdx.x >> 6, lane = threadIdx.x & 63;
  int e = blockIdx.x * 4 + wv;
  int i = tar[e], j = tar[E_TAR + e];
  int di = deg[i], dj = deg[j];
  int a = (di <= dj) ? i : j;
  int b = (di <= dj) ? j : i;
  int da = min(di, dj);
  if (lane == 0) cnts[wv] = 0;
  __syncthreads();
  const unsigned* mb = mask + (size_t)b * WPR;
  if (da <= CSR_MAX) {
    const int* la = csr + (size_t)a * CSR_MAX;
    for (int t = lane; t < da; t += 64) {
      int n = la[t];
      if ((mb[n >> 5] >> (n & 31)) & 1u) {
        int p = atomicAdd(&cnts[wv], 1);
        lists[wv][p] = n;              // da <= 128 so p < 256 always
      }
    }
  } else {
    const unsigned* ma = mask + (size_t)a * WPR;
    for (int w = lane; w < WUSED; w += 64) {
      unsigned v = ma[w] & mb[w];
      while (v) {
        int bit = __ffs(v) - 1;
        v &= v - 1;
        int p = atomicAdd(&cnts[wv], 1);
        if (p < 256) lists[wv][p] = w * 32 + bit;
      }
    }
  }
  __syncthreads();
  int n = cnts[wv]; if (n > 256) n = 256;
  float a0 = 0.f, a1 = 0.f;
  for (int t = 0; t < n; ++t) {
    const float* xr = x + (size_t)lists[wv][t] * IN_CH;
    a0 += xr[lane];
    a1 += xr[lane + 64];
  }
  cnx[(size_t)e * IN_CH + lane] = a0;
  cnx[(size_t)e * IN_CH + 64 + lane] = a1;
}

// ---------- weight transpose-convert: W[K][N] f32 -> Wt[N][K] bf16 ----------
__global__ void prep_w(const float* W1, const float* W2, const float* W3,
                       const float* Wij1, const float* Wij2, const float* Wl1,
                       unsigned short* wts) {
  int bid = blockIdx.x;
  const float* W; unsigned short* O; int K, t;
  // tiles: W1:32 W2:64 W3:64 Wij1:32 Wij2:64 Wl1:64 (32x32 tiles, N=256 always)
  if      (bid <  32) { W = W1;   O = wts;          K = 128; t = bid; }
  else if (bid <  96) { W = W2;   O = wts + 32768;  K = 256; t = bid - 32; }
  else if (bid < 160) { W = W3;   O = wts + 98304;  K = 256; t = bid - 96; }
  else if (bid < 192) { W = Wij1; O = wts + 163840; K = 128; t = bid - 160; }
  else if (bid < 256) { W = Wij2; O = wts + 196608; K = 256; t = bid - 192; }
  else                { W = Wl1;  O = wts + 262144; K = 256; t = bid - 256; }
  const int N = 256;
  int tpk = K / 32;
  int tk = t % tpk, tn = t / tpk;
  __shared__ float tile[32][33];
  int tid = threadIdx.x;
  int c = tid & 31, r0 = tid >> 5;   // 8 row-groups
  #pragma unroll
  for (int rr = 0; rr < 32; rr += 8)
    tile[r0 + rr][c] = W[(size_t)(tk * 32 + r0 + rr) * N + tn * 32 + c];
  __syncthreads();
  #pragma unroll
  for (int rr = 0; rr < 32; rr += 8)
    O[(size_t)(tn * 32 + r0 + rr) * K + tk * 32 + c] = f2bf(tile[c][r0 + rr]);
}

// ---------- fused MLP chain ----------
// One block = 32 edge-rows through all layers. 512 threads = 8 waves (2x4):
// wave covers rows wm..wm+15, cols wn..wn+63 of each 32x256 layer output.
template<int K>
__device__ __forceinline__ void gemm_core(const unsigned short (*A)[264],
                                          const unsigned short* __restrict__ Wt,
                                          int lane, int wm, int wn, f32x4* acc) {
  int l15 = lane & 15, kg = (lane >> 4) * 8;
  const unsigned short* wb = Wt + (size_t)(wn + l15) * K + kg;
  bf16x8 bc[4], bn_[4];
  #pragma unroll
  for (int f = 0; f < 4; ++f) bc[f] = *(const bf16x8*)(wb + f * 16 * K);
  #pragma unroll
  for (int k0 = 0; k0 < K; k0 += 32) {
    bf16x8 a = *(const bf16x8*)&A[wm + l15][k0 + kg];
    if (k0 + 32 < K) {
      #pragma unroll
      for (int f = 0; f < 4; ++f) bn_[f] = *(const bf16x8*)(wb + f * 16 * K + k0 + 32);
    }
    #pragma unroll
    for (int f = 0; f < 4; ++f)
      acc[f] = __builtin_amdgcn_mfma_f32_16x16x32_bf16(a, bc[f], acc[f], 0, 0, 0);
    #pragma unroll
    for (int f = 0; f < 4; ++f) bc[f] = bn_[f];
  }
}

__device__ __forceinline__ void epi_store(unsigned short (*dst)[264], f32x4* acc,
                                          const float* __restrict__ bias, bool relu,
                                          int lane, int wm, int wn) {
  int l15 = lane & 15, rq = (lane >> 4) * 4;
  #pragma unroll
  for (int f = 0; f < 4; ++f) {
    float bv = bias[wn + f * 16 + l15];
    #pragma unroll
    for (int i = 0; i < 4; ++i) {
      float v = acc[f][i] + bv;
      if (relu) v = fmaxf(v, 0.f);
      dst[wm + rq + i][wn + f * 16 + l15] = f2bf(v);
    }
  }
}

__global__ __launch_bounds__(512) void fused_mlp(
    const float* __restrict__ cn_x, const float* __restrict__ x, const int* __restrict__ tar,
    const unsigned short* __restrict__ wts,
    const float* __restrict__ b1, const float* __restrict__ b2, const float* __restrict__ b3,
    const float* __restrict__ bij1, const float* __restrict__ bij2, const float* __restrict__ bl1,
    const float* __restrict__ Wl2, const float* __restrict__ bl2,
    const float* __restrict__ betaPtr, float* __restrict__ out)
{
  __shared__ unsigned short P[BM][264];
  __shared__ unsigned short Q[BM][264];
  const unsigned short* Wt1   = wts;
  const unsigned short* Wt2   = wts + 32768;
  const unsigned short* Wt3   = wts + 98304;
  const unsigned short* Wtij1 = wts + 163840;
  const unsigned short* Wtij2 = wts + 196608;
  const unsigned short* Wtl1  = wts + 262144;

  int m0 = blockIdx.x * BM;
  int tid = threadIdx.x;
  int lane = tid & 63, wv = tid >> 6;
  int wm = (wv >> 2) * 16;       // 0 or 16
  int wn = (wv & 3) * 64;        // 0..192
  float beta_v = betaPtr[0];

  // load cn_x rows -> P (bf16)
  {
    int row = tid >> 4, seg = tid & 15;
    const float* src = cn_x + (size_t)(m0 + row) * IN_CH + seg * 8;
    f32x4 u0 = *(const f32x4*)src, u1 = *(const f32x4*)(src + 4);
    unsigned short tmp[8];
    #pragma unroll
    for (int u = 0; u < 4; ++u) { tmp[u] = f2bf(u0[u]); tmp[4 + u] = f2bf(u1[u]); }
    *(bf16x8*)&P[row][seg * 8] = *(bf16x8*)tmp;
  }
  __syncthreads();

  f32x4 acc[4];
  // L1: Q = relu(P @ Wt1 + b1), K=128
  #pragma unroll
  for (int f = 0; f < 4; ++f) acc[f] = (f32x4){0.f, 0.f, 0.f, 0.f};
  gemm_core<128>(P, Wt1, lane, wm, wn, acc);
  epi_store(Q, acc, b1, true, lane, wm, wn);
  __syncthreads();

  // L2: P = relu(Q @ Wt2 + b2), K=256
  #pragma unroll
  for (int f = 0; f < 4; ++f) acc[f] = (f32x4){0.f, 0.f, 0.f, 0.f};
  gemm_core<256>(Q, Wt2, lane, wm, wn, acc);
  epi_store(P, acc, b2, true, lane, wm, wn);
  __syncthreads();

  // L3: xcn (regs) = P @ Wt3 + b3, K=256
  f32x4 xcn[4];
  #pragma unroll
  for (int f = 0; f < 4; ++f) xcn[f] = (f32x4){0.f, 0.f, 0.f, 0.f};
  gemm_core<256>(P, Wt3, lane, wm, wn, xcn);
  {
    int l15 = lane & 15;
    #pragma unroll
    for (int f = 0; f < 4; ++f) {
      float bv = b3[wn + f * 16 + l15];
      #pragma unroll
      for (int i = 0; i < 4; ++i) xcn[f][i] += bv;
    }
  }
  __syncthreads();   // all P reads done before overwrite

  // gather xi*xj -> P (bf16)
  {
    int row = tid >> 4, seg = tid & 15;
    int gi = tar[m0 + row], gj = tar[E_TAR + m0 + row];
    const float* xi = x + (size_t)gi * IN_CH + seg * 8;
    const float* xj = x + (size_t)gj * IN_CH + seg * 8;
    f32x4 i0 = *(const f32x4*)xi, i1 = *(const f32x4*)(xi + 4);
    f32x4 j0 = *(const f32x4*)xj, j1 = *(const f32x4*)(xj + 4);
    unsigned short tmp[8];
    #pragma unroll
    for (int u = 0; u < 4; ++u) {
      tmp[u] = f2bf(i0[u] * j0[u]);
      tmp[4 + u] = f2bf(i1[u] * j1[u]);
    }
    *(bf16x8*)&P[row][seg * 8] = *(bf16x8*)tmp;
  }
  __syncthreads();

  // L4: Q = relu(P @ Wtij1 + bij1), K=128
  #pragma unroll
  for (int f = 0; f < 4; ++f) acc[f] = (f32x4){0.f, 0.f, 0.f, 0.f};
  gemm_core<128>(P, Wtij1, lane, wm, wn, acc);
  epi_store(Q, acc, bij1, true, lane, wm, wn);
  __syncthreads();

  // L5: P = (Q @ Wtij2 + bij2) + beta*xcn   (no relu)
  #pragma unroll
  for (int f = 0; f < 4; ++f) acc[f] = (f32x4){0.f, 0.f, 0.f, 0.f};
  gemm_core<256>(Q, Wtij2, lane, wm, wn, acc);
  {
    int l15 = lane & 15, rq = (lane >> 4) * 4;
    #pragma unroll
    for (int f = 0; f < 4; ++f) {
      float bv = bij2[wn + f * 16 + l15];
      #pragma unroll
      for (int i = 0; i < 4; ++i) {
        float v = acc[f][i] + bv + beta_v * xcn[f][i];
        P[wm + rq + i][wn + f * 16 + l15] = f2bf(v);
      }
    }
  }
  __syncthreads();

  // L6: Q = relu(P @ Wtl1 + bl1), K=256
  #pragma unroll
  for (int f = 0; f < 4; ++f) acc[f] = (f32x4){0.f, 0.f, 0.f, 0.f};
  gemm_core<256>(P, Wtl1, lane, wm, wn, acc);
  epi_store(Q, acc, bl1, true, lane, wm, wn);
  __syncthreads();

  // final: out[row] = Q[row,:] . Wl2 + bl2  (8 waves x 4 rows)
  {
    f32x4 w2v = *(const f32x4*)&Wl2[lane * 4];
    float bl2v = bl2[0];
    #pragma unroll
    for (int rr = 0; rr < 4; ++rr) {
      int r = wv * 4 + rr;
      bf16x4 q = *(const bf16x4*)&Q[r][lane * 4];
      float s = 0.f;
      #pragma unroll
      for (int u = 0; u < 4; ++u) s += bf2f((unsigned short)q[u]) * w2v[u];
      #pragma unroll
      for (int off = 32; off; off >>= 1) s += __shfl_down(s, off);
      if (lane == 0) out[m0 + r] = s + bl2v;
    }
  }
}

extern "C" void kernel_launch(void* const* d_in, const int* in_sizes, int n_in,
                              void* d_out, int out_size, void* d_ws, size_t ws_size,
                              hipStream_t stream) {
  const float* x      = (const float*)d_in[0];
  const int*   adj_r  = (const int*)d_in[1];
  const int*   adj_c  = (const int*)d_in[2];
  const int*   tar    = (const int*)d_in[3];
  const float* beta   = (const float*)d_in[4];
  const float* W1     = (const float*)d_in[5];
  const float* b1     = (const float*)d_in[6];
  const float* W2     = (const float*)d_in[7];
  const float* b2     = (const float*)d_in[8];
  const float* W3     = (const float*)d_in[9];
  const float* b3     = (const float*)d_in[10];
  const float* Wij1   = (const float*)d_in[11];
  const float* bij1   = (const float*)d_in[12];
  const float* Wij2   = (const float*)d_in[13];
  const float* bij2   = (const float*)d_in[14];
  const float* Wl1    = (const float*)d_in[15];
  const float* bl1    = (const float*)d_in[16];
  const float* Wl2    = (const float*)d_in[17];
  const float* bl2    = (const float*)d_in[18];

  char* ws = (char*)d_ws;
  unsigned*       mask = (unsigned*)ws;                                   // 12.8 MB
  int*            deg  = (int*)(ws + (size_t)14 * 1024 * 1024);           // 40 KB
  int*            csr  = (int*)(ws + (size_t)15 * 1024 * 1024);           // 5.12 MB
  float*          cnx  = (float*)(ws + (size_t)21 * 1024 * 1024);         // 4 MB
  unsigned short* wts  = (unsigned short*)(ws + (size_t)26 * 1024 * 1024);// 656 KB

  prep_w<<<320, 256, 0, stream>>>(W1, W2, W3, Wij1, Wij2, Wl1, wts);
  fill_zero<<<3200, 256, 0, stream>>>((uint4*)mask, MASK_WORDS / 4);
  scatter_adj<<<(N_EDGES + 255) / 256, 256, 0, stream>>>(adj_r, adj_c, mask);
  csr_build<<<N_NODES / 4, 256, 0, stream>>>(mask, deg, csr);
  cn_gather_csr<<<E_TAR / 4, 256, 0, stream>>>(mask, deg, csr, tar, x, cnx);
  fused_mlp<<<E_TAR / BM, 512, 0, stream>>>(cnx, x, tar, wts,
                                            b1, b2, b3, bij1, bij2, bl1,
                                            Wl2, bl2, beta, (float*)d_out);
}

// Round 4
// 77.001 us; speedup vs baseline: 1.1470x; 1.0748x over previous
//
#include <hip/hip_runtime.h>
#include <hip/hip_bf16.h>

#define N_NODES 10000
#define IN_CH 128
#define HID 256
#define E_TAR 8192
#define N_EDGES 320000
#define WPR 320          // bitmask words per row (313 used, padded)
#define WUSED 313
#define MASK_WORDS (N_NODES * WPR)   // 12.8 MB
#define CSR_MAX 128
#define BM 32

typedef short bf16x8 __attribute__((ext_vector_type(8)));
typedef short bf16x4 __attribute__((ext_vector_type(4)));
typedef float f32x4 __attribute__((ext_vector_type(4)));

__device__ __forceinline__ unsigned short f2bf(float f) {
  union { float f; unsigned u; } v; v.f = f;
  unsigned r = v.u + 0x7fffu + ((v.u >> 16) & 1u);  // RNE
  return (unsigned short)(r >> 16);
}
__device__ __forceinline__ float bf2f(unsigned short h) {
  union { unsigned u; float f; } v; v.u = ((unsigned)h) << 16; return v.f;
}

// ---------- zero mask (12.8MB) + deg (40KB), contiguous ----------
__global__ void fill_zero(uint4* __restrict__ p, int n4) {
  int i = blockIdx.x * 256 + threadIdx.x;
  int stride = gridDim.x * 256;
  uint4 z = {0u, 0u, 0u, 0u};
  for (; i < n4; i += stride) p[i] = z;
}

// scatter edge bits; the 0->1 winner appends to the (dedup'd) CSR list.
__global__ void scatter_adj(const int* __restrict__ row, const int* __restrict__ col,
                            unsigned* __restrict__ mask, int* __restrict__ deg,
                            int* __restrict__ csr) {
  int k = blockIdx.x * 256 + threadIdx.x;
  if (k < N_EDGES) {
    int r = row[k], c = col[k];
    unsigned bit = 1u << (c & 31);
    unsigned old = atomicOr(&mask[(size_t)r * WPR + (c >> 5)], bit);
    if (!(old & bit)) {
      int p = atomicAdd(&deg[r], 1);
      if (p < CSR_MAX) csr[(size_t)r * CSR_MAX + p] = c;
    }
  }
}

// ---------- common-neighbor gather: one wave per target edge ----------
__global__ void cn_gather_csr(const unsigned* __restrict__ mask, const int* __restrict__ deg,
                              const int* __restrict__ csr, const int* __restrict__ tar,
                              const float* __restrict__ x, float* __restrict__ cnx) {
  __shared__ int lists[4][256];
  __shared__ int cnts[4];
  int wv = threadIdx.x >> 6, lane = threadIdx.x & 63;
  int e = blockIdx.x * 4 + wv;
  int i = tar[e], j = tar[E_TAR + e];
  int di = deg[i], dj = deg[j];
  int a = (di <= dj) ? i : j;
  int b = (di <= dj) ? j : i;
  int da = min(di, dj);
  if (lane == 0) cnts[wv] = 0;
  __syncthreads();
  const unsigned* mb = mask + (size_t)b * WPR;
  if (da <= CSR_MAX) {
    const int* la = csr + (size_t)a * CSR_MAX;
    for (int t = lane; t < da; t += 64) {
      int n = la[t];
      if ((mb[n >> 5] >> (n & 31)) & 1u) {
        int p = atomicAdd(&cnts[wv], 1);
        lists[wv][p] = n;              // #common <= da <= 128 < 256
      }
    }
  } else {
    const unsigned* ma = mask + (size_t)a * WPR;
    for (int w = lane; w < WUSED; w += 64) {
      unsigned v = ma[w] & mb[w];
      while (v) {
        int bit = __ffs(v) - 1;
        v &= v - 1;
        int p = atomicAdd(&cnts[wv], 1);
        if (p < 256) lists[wv][p] = w * 32 + bit;
      }
    }
  }
  __syncthreads();
  int n = cnts[wv]; if (n > 256) n = 256;
  float a0 = 0.f, a1 = 0.f;
  for (int t = 0; t < n; ++t) {
    const float* xr = x + (size_t)lists[wv][t] * IN_CH;
    a0 += xr[lane];
    a1 += xr[lane + 64];
  }
  cnx[(size_t)e * IN_CH + lane] = a0;
  cnx[(size_t)e * IN_CH + 64 + lane] = a1;
}

// ---------- weight transpose-convert: W[K][N] f32 -> Wt[N][K] bf16 ----------
__global__ void prep_w(const float* W1, const float* W2, const float* W3,
                       const float* Wij1, const float* Wij2, const float* Wl1,
                       unsigned short* wts) {
  int bid = blockIdx.x;
  const float* W; unsigned short* O; int K, t;
  if      (bid <  32) { W = W1;   O = wts;          K = 128; t = bid; }
  else if (bid <  96) { W = W2;   O = wts + 32768;  K = 256; t = bid - 32; }
  else if (bid < 160) { W = W3;   O = wts + 98304;  K = 256; t = bid - 96; }
  else if (bid < 192) { W = Wij1; O = wts + 163840; K = 128; t = bid - 160; }
  else if (bid < 256) { W = Wij2; O = wts + 196608; K = 256; t = bid - 192; }
  else                { W = Wl1;  O = wts + 262144; K = 256; t = bid - 256; }
  const int N = 256;
  int tpk = K / 32;
  int tk = t % tpk, tn = t / tpk;
  __shared__ float tile[32][33];
  int tid = threadIdx.x;
  int c = tid & 31, r0 = tid >> 5;
  #pragma unroll
  for (int rr = 0; rr < 32; rr += 8)
    tile[r0 + rr][c] = W[(size_t)(tk * 32 + r0 + rr) * N + tn * 32 + c];
  __syncthreads();
  #pragma unroll
  for (int rr = 0; rr < 32; rr += 8)
    O[(size_t)(tn * 32 + r0 + rr) * K + tk * 32 + c] = f2bf(tile[c][r0 + rr]);
}

// ---------- fused MLP ----------
// 8 waves, wave wv owns cols wv*32..wv*32+31, all 32 rows. B fully register-
// resident per layer (16 x bf16x8); loads for layer n+1 issue right after the
// last MFMA use of layer n's B regs -> one latency burst per layer, hidden
// under epilogue + barrier.
template<int KN>
__device__ __forceinline__ void loadB(const unsigned short* __restrict__ Wt,
                                      int wn, int l15, int kg,
                                      bf16x8* b0, bf16x8* b1) {
  const unsigned short* p0 = Wt + (size_t)(wn + l15) * KN + kg;
  const unsigned short* p1 = Wt + (size_t)(wn + 16 + l15) * KN + kg;
  #pragma unroll
  for (int s = 0; s < KN / 32; ++s) {
    b0[s] = *(const bf16x8*)(p0 + s * 32);
    b1[s] = *(const bf16x8*)(p1 + s * 32);
  }
}

template<int K>
__device__ __forceinline__ void computeL(const unsigned short (*A)[264],
                                         const bf16x8* b0, const bf16x8* b1,
                                         int l15, int kg, f32x4 acc[2][2]) {
  #pragma unroll
  for (int s = 0; s < K / 32; ++s) {
    bf16x8 a0 = *(const bf16x8*)&A[l15][s * 32 + kg];
    bf16x8 a1 = *(const bf16x8*)&A[16 + l15][s * 32 + kg];
    acc[0][0] = __builtin_amdgcn_mfma_f32_16x16x32_bf16(a0, b0[s], acc[0][0], 0, 0, 0);
    acc[1][0] = __builtin_amdgcn_mfma_f32_16x16x32_bf16(a1, b0[s], acc[1][0], 0, 0, 0);
    acc[0][1] = __builtin_amdgcn_mfma_f32_16x16x32_bf16(a0, b1[s], acc[0][1], 0, 0, 0);
    acc[1][1] = __builtin_amdgcn_mfma_f32_16x16x32_bf16(a1, b1[s], acc[1][1], 0, 0, 0);
  }
}

__global__ __launch_bounds__(512, 2) void fused_mlp(
    const float* __restrict__ cn_x, const float* __restrict__ x, const int* __restrict__ tar,
    const unsigned short* __restrict__ wts,
    const float* __restrict__ b1, const float* __restrict__ b2, const float* __restrict__ b3,
    const float* __restrict__ bij1, const float* __restrict__ bij2, const float* __restrict__ bl1,
    const float* __restrict__ Wl2, const float* __restrict__ bl2,
    const float* __restrict__ betaPtr, float* __restrict__ out)
{
  __shared__ unsigned short P[BM][264];
  __shared__ unsigned short Q[BM][264];
  const unsigned short* Wt1   = wts;
  const unsigned short* Wt2   = wts + 32768;
  const unsigned short* Wt3   = wts + 98304;
  const unsigned short* Wtij1 = wts + 163840;
  const unsigned short* Wtij2 = wts + 196608;
  const unsigned short* Wtl1  = wts + 262144;

  int m0 = blockIdx.x * BM;
  int tid = threadIdx.x;
  int lane = tid & 63, wv = tid >> 6;
  int wn = wv * 32;
  int l15 = lane & 15, kg = (lane >> 4) * 8, rq = (lane >> 4) * 4;

  bf16x8 B0[8], B1[8];
  loadB<128>(Wt1, wn, l15, kg, B0, B1);   // issue ASAP; consumed after 1st barrier

  // prefetch xi/xj rows (used at L4) and all epilogue biases
  int row = tid >> 4, seg = tid & 15;
  int gi = tar[m0 + row], gj = tar[E_TAR + m0 + row];
  const float* xip = x + (size_t)gi * IN_CH + seg * 8;
  const float* xjp = x + (size_t)gj * IN_CH + seg * 8;
  f32x4 xi0 = *(const f32x4*)xip, xi1 = *(const f32x4*)(xip + 4);
  f32x4 xj0 = *(const f32x4*)xjp, xj1 = *(const f32x4*)(xjp + 4);
  float bv1[2]   = { b1[wn + l15],   b1[wn + 16 + l15] };
  float bv2[2]   = { b2[wn + l15],   b2[wn + 16 + l15] };
  float bv3[2]   = { b3[wn + l15],   b3[wn + 16 + l15] };
  float bvij1[2] = { bij1[wn + l15], bij1[wn + 16 + l15] };
  float bvij2[2] = { bij2[wn + l15], bij2[wn + 16 + l15] };
  float bvl1[2]  = { bl1[wn + l15],  bl1[wn + 16 + l15] };
  float beta_v = betaPtr[0];
  f32x4 w2v = *(const f32x4*)&Wl2[lane * 4];

  // cn_x rows -> P (bf16)
  {
    const float* src = cn_x + (size_t)(m0 + row) * IN_CH + seg * 8;
    f32x4 u0 = *(const f32x4*)src, u1 = *(const f32x4*)(src + 4);
    unsigned short tmp[8];
    #pragma unroll
    for (int u = 0; u < 4; ++u) { tmp[u] = f2bf(u0[u]); tmp[4 + u] = f2bf(u1[u]); }
    *(bf16x8*)&P[row][seg * 8] = *(bf16x8*)tmp;
  }
  __syncthreads();

  f32x4 acc[2][2];
  #define ZACC { acc[0][0]=(f32x4){0,0,0,0}; acc[0][1]=(f32x4){0,0,0,0}; \
                 acc[1][0]=(f32x4){0,0,0,0}; acc[1][1]=(f32x4){0,0,0,0}; }
  #define EPI(dst, bv, RELU) { \
    _Pragma("unroll") for (int nf = 0; nf < 2; ++nf) { \
      int cg = wn + nf * 16 + l15; \
      _Pragma("unroll") for (int m = 0; m < 2; ++m) \
        _Pragma("unroll") for (int i = 0; i < 4; ++i) { \
          float v = acc[m][nf][i] + bv[nf]; \
          if (RELU) v = fmaxf(v, 0.f); \
          dst[m * 16 + rq + i][cg] = f2bf(v); \
        } \
    } }

  // L1: Q = relu(P @ W1 + b1)
  ZACC; computeL<128>(P, B0, B1, l15, kg, acc);
  loadB<256>(Wt2, wn, l15, kg, B0, B1);
  EPI(Q, bv1, 1);
  __syncthreads();

  // L2: P = relu(Q @ W2 + b2)
  ZACC; computeL<256>(Q, B0, B1, l15, kg, acc);
  loadB<256>(Wt3, wn, l15, kg, B0, B1);
  EPI(P, bv2, 1);
  __syncthreads();

  // L3: xcn (regs) = P @ W3 + b3
  f32x4 xcn[2][2];
  xcn[0][0]=(f32x4){0,0,0,0}; xcn[0][1]=(f32x4){0,0,0,0};
  xcn[1][0]=(f32x4){0,0,0,0}; xcn[1][1]=(f32x4){0,0,0,0};
  computeL<256>(P, B0, B1, l15, kg, xcn);
  loadB<128>(Wtij1, wn, l15, kg, B0, B1);
  #pragma unroll
  for (int nf = 0; nf < 2; ++nf)
    #pragma unroll
    for (int m = 0; m < 2; ++m)
      #pragma unroll
      for (int i = 0; i < 4; ++i) xcn[m][nf][i] += bv3[nf];
  __syncthreads();   // all P reads done before overwrite

  // gather xi*xj -> P (regs were prefetched at entry)
  {
    unsigned short tmp[8];
    #pragma unroll
    for (int u = 0; u < 4; ++u) {
      tmp[u] = f2bf(xi0[u] * xj0[u]);
      tmp[4 + u] = f2bf(xi1[u] * xj1[u]);
    }
    *(bf16x8*)&P[row][seg * 8] = *(bf16x8*)tmp;
  }
  __syncthreads();

  // L4: Q = relu(P @ Wij1 + bij1)
  ZACC; computeL<128>(P, B0, B1, l15, kg, acc);
  loadB<256>(Wtij2, wn, l15, kg, B0, B1);
  EPI(Q, bvij1, 1);
  __syncthreads();

  // L5: P = (Q @ Wij2 + bij2) + beta*xcn
  ZACC; computeL<256>(Q, B0, B1, l15, kg, acc);
  loadB<256>(Wtl1, wn, l15, kg, B0, B1);
  #pragma unroll
  for (int nf = 0; nf < 2; ++nf) {
    int cg = wn + nf * 16 + l15;
    #pragma unroll
    for (int m = 0; m < 2; ++m)
      #pragma unroll
      for (int i = 0; i < 4; ++i) {
        float v = acc[m][nf][i] + bvij2[nf] + beta_v * xcn[m][nf][i];
        P[m * 16 + rq + i][cg] = f2bf(v);
      }
  }
  __syncthreads();

  // L6: Q = relu(P @ Wl1 + bl1)
  ZACC; computeL<256>(P, B0, B1, l15, kg, acc);
  EPI(Q, bvl1, 1);
  __syncthreads();

  // final: out[r] = Q[r,:] . Wl2 + bl2 (8 waves x 4 rows)
  {
    float bl2v = bl2[0];
    #pragma unroll
    for (int rr = 0; rr < 4; ++rr) {
      int r = wv * 4 + rr;
      bf16x4 q = *(const bf16x4*)&Q[r][lane * 4];
      float s = 0.f;
      #pragma unroll
      for (int u = 0; u < 4; ++u) s += bf2f((unsigned short)q[u]) * w2v[u];
      #pragma unroll
      for (int off = 32; off; off >>= 1) s += __shfl_down(s, off);
      if (lane == 0) out[m0 + r] = s + bl2v;
    }
  }
}

extern "C" void kernel_launch(void* const* d_in, const int* in_sizes, int n_in,
                              void* d_out, int out_size, void* d_ws, size_t ws_size,
                              hipStream_t stream) {
  const float* x      = (const float*)d_in[0];
  const int*   adj_r  = (const int*)d_in[1];
  const int*   adj_c  = (const int*)d_in[2];
  const int*   tar    = (const int*)d_in[3];
  const float* beta   = (const float*)d_in[4];
  const float* W1     = (const float*)d_in[5];
  const float* b1     = (const float*)d_in[6];
  const float* W2     = (const float*)d_in[7];
  const float* b2     = (const float*)d_in[8];
  const float* W3     = (const float*)d_in[9];
  const float* b3     = (const float*)d_in[10];
  const float* Wij1   = (const float*)d_in[11];
  const float* bij1   = (const float*)d_in[12];
  const float* Wij2   = (const float*)d_in[13];
  const float* bij2   = (const float*)d_in[14];
  const float* Wl1    = (const float*)d_in[15];
  const float* bl1    = (const float*)d_in[16];
  const float* Wl2    = (const float*)d_in[17];
  const float* bl2    = (const float*)d_in[18];

  char* ws = (char*)d_ws;
  unsigned*       mask = (unsigned*)ws;                                   // 12.8 MB
  int*            deg  = (int*)(ws + (size_t)MASK_WORDS * 4);             // 40 KB (contiguous for fused zero)
  int*            csr  = (int*)(ws + (size_t)15 * 1024 * 1024);           // 5.12 MB
  float*          cnx  = (float*)(ws + (size_t)21 * 1024 * 1024);         // 4 MB
  unsigned short* wts  = (unsigned short*)(ws + (size_t)26 * 1024 * 1024);// 656 KB

  prep_w<<<320, 256, 0, stream>>>(W1, W2, W3, Wij1, Wij2, Wl1, wts);
  fill_zero<<<3200, 256, 0, stream>>>((uint4*)mask, (MASK_WORDS + N_NODES) / 4);
  scatter_adj<<<(N_EDGES + 255) / 256, 256, 0, stream>>>(adj_r, adj_c, mask, deg, csr);
  cn_gather_csr<<<E_TAR / 4, 256, 0, stream>>>(mask, deg, csr, tar, x, cnx);
  fused_mlp<<<E_TAR / BM, 512, 0, stream>>>(cnx, x, tar, wts,
                                            b1, b2, b3, bij1, bij2, bl1,
                                            Wl2, bl2, beta, (float*)d_out);
}

// Round 5
// 72.712 us; speedup vs baseline: 1.2146x; 1.0590x over previous
//
#include <hip/hip_runtime.h>
#include <hip/hip_bf16.h>

#define N_NODES 10000
#define IN_CH 128
#define HID 256
#define E_TAR 8192
#define N_EDGES 320000
#define WPR 320          // bitmask words per row (313 used, padded)
#define WUSED 313
#define MASK_WORDS (N_NODES * WPR)   // 12.8 MB
#define CSR_MAX 128
#define BM 32

typedef short bf16x8 __attribute__((ext_vector_type(8)));
typedef short bf16x4 __attribute__((ext_vector_type(4)));
typedef float f32x4 __attribute__((ext_vector_type(4)));

__device__ __forceinline__ unsigned short f2bf(float f) {
  union { float f; unsigned u; } v; v.f = f;
  unsigned r = v.u + 0x7fffu + ((v.u >> 16) & 1u);  // RNE
  return (unsigned short)(r >> 16);
}
__device__ __forceinline__ float bf2f(unsigned short h) {
  union { unsigned u; float f; } v; v.u = ((unsigned)h) << 16; return v.f;
}

// ---------- kernel A: weight transpose-convert (blocks 0..319) ----------
// ----------           + zero mask+deg           (blocks 320..3519) ------
__global__ void prep_and_fill(const float* __restrict__ W1, const float* __restrict__ W2,
                              const float* __restrict__ W3, const float* __restrict__ Wij1,
                              const float* __restrict__ Wij2, const float* __restrict__ Wl1,
                              unsigned short* __restrict__ wts,
                              uint4* __restrict__ zbase, int n4) {
  if (blockIdx.x >= 320) {
    int i = (blockIdx.x - 320) * 256 + threadIdx.x;
    int stride = 3200 * 256;
    uint4 z = {0u, 0u, 0u, 0u};
    for (; i < n4; i += stride) zbase[i] = z;
    return;
  }
  int bid = blockIdx.x;
  const float* W; unsigned short* O; int K, t;
  if      (bid <  32) { W = W1;   O = wts;          K = 128; t = bid; }
  else if (bid <  96) { W = W2;   O = wts + 32768;  K = 256; t = bid - 32; }
  else if (bid < 160) { W = W3;   O = wts + 98304;  K = 256; t = bid - 96; }
  else if (bid < 192) { W = Wij1; O = wts + 163840; K = 128; t = bid - 160; }
  else if (bid < 256) { W = Wij2; O = wts + 196608; K = 256; t = bid - 192; }
  else                { W = Wl1;  O = wts + 262144; K = 256; t = bid - 256; }
  const int N = 256;
  int tpk = K / 32;
  int tk = t % tpk, tn = t / tpk;
  __shared__ float tile[32][33];
  int tid = threadIdx.x;
  int c = tid & 31, r0 = tid >> 5;
  #pragma unroll
  for (int rr = 0; rr < 32; rr += 8)
    tile[r0 + rr][c] = W[(size_t)(tk * 32 + r0 + rr) * N + tn * 32 + c];
  __syncthreads();
  #pragma unroll
  for (int rr = 0; rr < 32; rr += 8)
    O[(size_t)(tn * 32 + r0 + rr) * K + tk * 32 + c] = f2bf(tile[c][r0 + rr]);
}

// ---------- kernel B: scatter bits; 0->1 winners append to dedup'd CSR ----------
__global__ void scatter_adj(const int* __restrict__ row, const int* __restrict__ col,
                            unsigned* __restrict__ mask, int* __restrict__ deg,
                            int* __restrict__ csr) {
  int k = blockIdx.x * 256 + threadIdx.x;
  if (k < N_EDGES) {
    int r = row[k], c = col[k];
    unsigned bit = 1u << (c & 31);
    unsigned old = atomicOr(&mask[(size_t)r * WPR + (c >> 5)], bit);
    if (!(old & bit)) {
      int p = atomicAdd(&deg[r], 1);
      if (p < CSR_MAX) csr[(size_t)r * CSR_MAX + p] = c;
    }
  }
}

// ---------- kernel C: CN gather + full MLP chain + final head ----------
template<int KN>
__device__ __forceinline__ void loadB(const unsigned short* __restrict__ Wt,
                                      int wn, int l15, int kg,
                                      bf16x8* b0, bf16x8* b1) {
  const unsigned short* p0 = Wt + (size_t)(wn + l15) * KN + kg;
  const unsigned short* p1 = Wt + (size_t)(wn + 16 + l15) * KN + kg;
  #pragma unroll
  for (int s = 0; s < KN / 32; ++s) {
    b0[s] = *(const bf16x8*)(p0 + s * 32);
    b1[s] = *(const bf16x8*)(p1 + s * 32);
  }
}

template<int K>
__device__ __forceinline__ void computeL(const unsigned short (*A)[264],
                                         const bf16x8* b0, const bf16x8* b1,
                                         int l15, int kg, f32x4 acc[2][2]) {
  #pragma unroll
  for (int s = 0; s < K / 32; ++s) {
    bf16x8 a0 = *(const bf16x8*)&A[l15][s * 32 + kg];
    bf16x8 a1 = *(const bf16x8*)&A[16 + l15][s * 32 + kg];
    acc[0][0] = __builtin_amdgcn_mfma_f32_16x16x32_bf16(a0, b0[s], acc[0][0], 0, 0, 0);
    acc[1][0] = __builtin_amdgcn_mfma_f32_16x16x32_bf16(a1, b0[s], acc[1][0], 0, 0, 0);
    acc[0][1] = __builtin_amdgcn_mfma_f32_16x16x32_bf16(a0, b1[s], acc[0][1], 0, 0, 0);
    acc[1][1] = __builtin_amdgcn_mfma_f32_16x16x32_bf16(a1, b1[s], acc[1][1], 0, 0, 0);
  }
}

__global__ __launch_bounds__(512, 2) void fused_all(
    const unsigned* __restrict__ mask, const int* __restrict__ deg,
    const int* __restrict__ csr, const int* __restrict__ tar,
    const float* __restrict__ x, const unsigned short* __restrict__ wts,
    const float* __restrict__ b1, const float* __restrict__ b2, const float* __restrict__ b3,
    const float* __restrict__ bij1, const float* __restrict__ bij2, const float* __restrict__ bl1,
    const float* __restrict__ Wl2, const float* __restrict__ bl2,
    const float* __restrict__ betaPtr, float* __restrict__ out)
{
  __shared__ unsigned short P[BM][264];
  __shared__ unsigned short Q[BM][264];
  const unsigned short* Wt1   = wts;
  const unsigned short* Wt2   = wts + 32768;
  const unsigned short* Wt3   = wts + 98304;
  const unsigned short* Wtij1 = wts + 163840;
  const unsigned short* Wtij2 = wts + 196608;
  const unsigned short* Wtl1  = wts + 262144;

  int m0 = blockIdx.x * BM;
  int tid = threadIdx.x;
  int lane = tid & 63, wv = tid >> 6;
  int wn = wv * 32;
  int l15 = lane & 15, kg = (lane >> 4) * 8, rq = (lane >> 4) * 4;

  bf16x8 B0[8], B1[8];
  loadB<128>(Wt1, wn, l15, kg, B0, B1);   // consumed after first barrier

  // prefetch epilogue constants + xi/xj rows (L4 input)
  int row = tid >> 4, seg = tid & 15;
  int gi = tar[m0 + row], gj = tar[E_TAR + m0 + row];
  const float* xip = x + (size_t)gi * IN_CH + seg * 8;
  const float* xjp = x + (size_t)gj * IN_CH + seg * 8;
  f32x4 xi0 = *(const f32x4*)xip, xi1 = *(const f32x4*)(xip + 4);
  f32x4 xj0 = *(const f32x4*)xjp, xj1 = *(const f32x4*)(xjp + 4);
  float bv1[2]   = { b1[wn + l15],   b1[wn + 16 + l15] };
  float bv2[2]   = { b2[wn + l15],   b2[wn + 16 + l15] };
  float bv3[2]   = { b3[wn + l15],   b3[wn + 16 + l15] };
  float bvij1[2] = { bij1[wn + l15], bij1[wn + 16 + l15] };
  float bvij2[2] = { bij2[wn + l15], bij2[wn + 16 + l15] };
  float bvl1[2]  = { bl1[wn + l15],  bl1[wn + 16 + l15] };
  float beta_v = betaPtr[0];
  f32x4 w2v = *(const f32x4*)&Wl2[lane * 4];

  // ---- CN gather: wave wv owns local rows wv*4..wv*4+3 ----
  float g0[4] = {0.f, 0.f, 0.f, 0.f}, g1[4] = {0.f, 0.f, 0.f, 0.f};
  #pragma unroll
  for (int q = 0; q < 4; ++q) {
    int e  = m0 + wv * 4 + q;
    int ti = tar[e], tj = tar[E_TAR + e];
    int di = deg[ti], dj = deg[tj];
    int a  = (di <= dj) ? ti : tj;
    int b  = (di <= dj) ? tj : ti;
    int da = min(di, dj);                 // wave-uniform
    const unsigned* mb = mask + (size_t)b * WPR;
    const int* la = csr + (size_t)a * CSR_MAX;
    int nit = (da + 63) >> 6;             // usually 1
    for (int it = 0; it < nit; ++it) {
      int t = it * 64 + lane;
      int n = 0; bool hit = false;
      if (t < da) {
        n = la[t];
        hit = (mb[n >> 5] >> (n & 31)) & 1u;
      }
      unsigned long long bal = __ballot(hit);
      while (bal) {                        // all 64 lanes accumulate each hit
        int src = __ffsll((unsigned long long)bal) - 1;
        bal &= bal - 1;
        int nb = __shfl(n, src);
        const float* xr = x + (size_t)nb * IN_CH;
        g0[q] += xr[lane];
        g1[q] += xr[lane + 64];
      }
    }
  }
  #pragma unroll
  for (int q = 0; q < 4; ++q) {
    int r = wv * 4 + q;
    P[r][lane]      = f2bf(g0[q]);
    P[r][64 + lane] = f2bf(g1[q]);
  }
  __syncthreads();

  f32x4 acc[2][2];
  #define ZACC { acc[0][0]=(f32x4){0,0,0,0}; acc[0][1]=(f32x4){0,0,0,0}; \
                 acc[1][0]=(f32x4){0,0,0,0}; acc[1][1]=(f32x4){0,0,0,0}; }
  #define EPI(dst, bv, RELU) { \
    _Pragma("unroll") for (int nf = 0; nf < 2; ++nf) { \
      int cg = wn + nf * 16 + l15; \
      _Pragma("unroll") for (int m = 0; m < 2; ++m) \
        _Pragma("unroll") for (int i = 0; i < 4; ++i) { \
          float v = acc[m][nf][i] + bv[nf]; \
          if (RELU) v = fmaxf(v, 0.f); \
          dst[m * 16 + rq + i][cg] = f2bf(v); \
        } \
    } }

  // L1: Q = relu(P @ W1 + b1), K=128
  ZACC; computeL<128>(P, B0, B1, l15, kg, acc);
  loadB<256>(Wt2, wn, l15, kg, B0, B1);
  EPI(Q, bv1, 1);
  __syncthreads();

  // L2: P = relu(Q @ W2 + b2)
  ZACC; computeL<256>(Q, B0, B1, l15, kg, acc);
  loadB<256>(Wt3, wn, l15, kg, B0, B1);
  EPI(P, bv2, 1);
  __syncthreads();

  // L3: xcn (regs) = P @ W3 + b3
  f32x4 xcn[2][2];
  xcn[0][0]=(f32x4){0,0,0,0}; xcn[0][1]=(f32x4){0,0,0,0};
  xcn[1][0]=(f32x4){0,0,0,0}; xcn[1][1]=(f32x4){0,0,0,0};
  computeL<256>(P, B0, B1, l15, kg, xcn);
  loadB<128>(Wtij1, wn, l15, kg, B0, B1);
  #pragma unroll
  for (int nf = 0; nf < 2; ++nf)
    #pragma unroll
    for (int m = 0; m < 2; ++m)
      #pragma unroll
      for (int i = 0; i < 4; ++i) xcn[m][nf][i] += bv3[nf];
  __syncthreads();   // all P reads done before overwrite

  // gather xi*xj -> P (prefetched at entry)
  {
    unsigned short tmp[8];
    #pragma unroll
    for (int u = 0; u < 4; ++u) {
      tmp[u] = f2bf(xi0[u] * xj0[u]);
      tmp[4 + u] = f2bf(xi1[u] * xj1[u]);
    }
    *(bf16x8*)&P[row][seg * 8] = *(bf16x8*)tmp;
  }
  __syncthreads();

  // L4: Q = relu(P @ Wij1 + bij1), K=128
  ZACC; computeL<128>(P, B0, B1, l15, kg, acc);
  loadB<256>(Wtij2, wn, l15, kg, B0, B1);
  EPI(Q, bvij1, 1);
  __syncthreads();

  // L5: P = (Q @ Wij2 + bij2) + beta*xcn
  ZACC; computeL<256>(Q, B0, B1, l15, kg, acc);
  loadB<256>(Wtl1, wn, l15, kg, B0, B1);
  #pragma unroll
  for (int nf = 0; nf < 2; ++nf) {
    int cg = wn + nf * 16 + l15;
    #pragma unroll
    for (int m = 0; m < 2; ++m)
      #pragma unroll
      for (int i = 0; i < 4; ++i) {
        float v = acc[m][nf][i] + bvij2[nf] + beta_v * xcn[m][nf][i];
        P[m * 16 + rq + i][cg] = f2bf(v);
      }
  }
  __syncthreads();

  // L6: Q = relu(P @ Wl1 + bl1)
  ZACC; computeL<256>(P, B0, B1, l15, kg, acc);
  EPI(Q, bvl1, 1);
  __syncthreads();

  // final: out[r] = Q[r,:] . Wl2 + bl2 (8 waves x 4 rows)
  {
    float bl2v = bl2[0];
    #pragma unroll
    for (int rr = 0; rr < 4; ++rr) {
      int r = wv * 4 + rr;
      bf16x4 q = *(const bf16x4*)&Q[r][lane * 4];
      float s = 0.f;
      #pragma unroll
      for (int u = 0; u < 4; ++u) s += bf2f((unsigned short)q[u]) * w2v[u];
      #pragma unroll
      for (int off = 32; off; off >>= 1) s += __shfl_down(s, off);
      if (lane == 0) out[m0 + r] = s + bl2v;
    }
  }
}

extern "C" void kernel_launch(void* const* d_in, const int* in_sizes, int n_in,
                              void* d_out, int out_size, void* d_ws, size_t ws_size,
                              hipStream_t stream) {
  const float* x      = (const float*)d_in[0];
  const int*   adj_r  = (const int*)d_in[1];
  const int*   adj_c  = (const int*)d_in[2];
  const int*   tar    = (const int*)d_in[3];
  const float* beta   = (const float*)d_in[4];
  const float* W1     = (const float*)d_in[5];
  const float* b1     = (const float*)d_in[6];
  const float* W2     = (const float*)d_in[7];
  const float* b2     = (const float*)d_in[8];
  const float* W3     = (const float*)d_in[9];
  const float* b3     = (const float*)d_in[10];
  const float* Wij1   = (const float*)d_in[11];
  const float* bij1   = (const float*)d_in[12];
  const float* Wij2   = (const float*)d_in[13];
  const float* bij2   = (const float*)d_in[14];
  const float* Wl1    = (const float*)d_in[15];
  const float* bl1    = (const float*)d_in[16];
  const float* Wl2    = (const float*)d_in[17];
  const float* bl2    = (const float*)d_in[18];

  char* ws = (char*)d_ws;
  unsigned*       mask = (unsigned*)ws;                                   // 12.8 MB
  int*            deg  = (int*)(ws + (size_t)MASK_WORDS * 4);             // 40 KB, contiguous for fused zero
  int*            csr  = (int*)(ws + (size_t)15 * 1024 * 1024);           // 5.12 MB
  unsigned short* wts  = (unsigned short*)(ws + (size_t)21 * 1024 * 1024);// 656 KB

  // A: weights transpose (320 blocks) + mask/deg zero (3200 blocks)
  prep_and_fill<<<3520, 256, 0, stream>>>(W1, W2, W3, Wij1, Wij2, Wl1, wts,
                                          (uint4*)mask, (MASK_WORDS + N_NODES) / 4);
  // B: adjacency scatter + dedup'd CSR
  scatter_adj<<<(N_EDGES + 255) / 256, 256, 0, stream>>>(adj_r, adj_c, mask, deg, csr);
  // C: everything else
  fused_all<<<E_TAR / BM, 512, 0, stream>>>(mask, deg, csr, tar, x, wts,
                                            b1, b2, b3, bij1, bij2, bl1,
                                            Wl2, bl2, beta, (float*)d_out);
}